// Round 1
// baseline (550.965 us; speedup 1.0000x reference)
//
#include <hip/hip_runtime.h>
#include <hip/hip_bf16.h>

// Problem constants
#define B_   8
#define TQ_  1024
#define TK_  1024
#define DIM_ 1024
#define H_   16
#define D_   64
#define SCALE_ 0.03125f   // DIM^-0.5
#define NEG_  -1.0e9f

typedef __attribute__((ext_vector_type(8))) short bf16x8;
typedef __attribute__((ext_vector_type(4))) float f32x4;
typedef __attribute__((ext_vector_type(4))) unsigned short u16x4;

typedef void __attribute__((address_space(3))) lds_void;
typedef const void __attribute__((address_space(1))) g_void;

__device__ __forceinline__ unsigned short f2bf(float f) {
  unsigned int u = __float_as_uint(f);
  u += 0x7fffu + ((u >> 16) & 1u);   // RNE to bf16
  return (unsigned short)(u >> 16);
}

// XOR swizzle for tiles with 128-byte rows: spreads the 16-row column reads
// across 8 distinct 16B slots -> <=2-way LDS bank conflict (free).
__device__ __forceinline__ int swz(int o) { return o ^ (((o >> 7) & 7) << 4); }

__device__ __forceinline__ void gload16(char* l, const char* g) {
  __builtin_amdgcn_global_load_lds((g_void*)g, (lds_void*)l, 16, 0, 0);
}

// ---------------------------------------------------------------- conversions
__global__ void cvt_f32_bf16(const float* __restrict__ in,
                             unsigned short* __restrict__ out, int n4) {
  int idx = blockIdx.x * blockDim.x + threadIdx.x;
  int stride = gridDim.x * blockDim.x;
  for (int i = idx; i < n4; i += stride) {
    f32x4 v = ((const f32x4*)in)[i];
    u16x4 o;
#pragma unroll
    for (int j = 0; j < 4; ++j) o[j] = f2bf(v[j]);
    ((u16x4*)out)[i] = o;
  }
}

// ------------------------------------------------------------ projection GEMM
// C[m][n] = sum_k A[m][k] * W[n][k] + bias[n]   (nn.Linear with W [out,in])
// mode 0: out is [B,H,T,64] bf16 (head-split, for Q,K)
// mode 1: out is [B,H,64,T] bf16 (V transposed, B-operand-ready)
__global__ __launch_bounds__(256)
void proj_gemm(const unsigned short* __restrict__ A,
               const unsigned short* __restrict__ W,
               const float* __restrict__ bias,
               unsigned short* __restrict__ out, int mode) {
  __shared__ char lds[32768];  // A tile [128][64]bf16 @0, W tile [128][64]bf16 @16384
  const int tid = threadIdx.x;
  const int lane = tid & 63, wid = tid >> 6;
  const int mb = blockIdx.x, nb = blockIdx.y;
  const int wrow = (wid >> 1) * 64, wcol = (wid & 1) * 64;

  f32x4 acc[4][4];
#pragma unroll
  for (int mi = 0; mi < 4; ++mi)
#pragma unroll
    for (int ni = 0; ni < 4; ++ni)
#pragma unroll
      for (int t = 0; t < 4; ++t) acc[mi][ni][t] = 0.f;

  const char* Ab = (const char*)A + (size_t)mb * 128 * 2048;
  const char* Wb = (const char*)W + (size_t)nb * 128 * 2048;

  for (int kt = 0; kt < 16; ++kt) {
    __syncthreads();
#pragma unroll
    for (int c = 0; c < 4; ++c) {
      int o = (wid * 4 + c) * 1024 + lane * 16;
      int l = swz(o);
      gload16(lds + (wid * 4 + c) * 1024,
              Ab + (size_t)(l >> 7) * 2048 + kt * 128 + (l & 127));
      gload16(lds + 16384 + (wid * 4 + c) * 1024,
              Wb + (size_t)(l >> 7) * 2048 + kt * 128 + (l & 127));
    }
    __syncthreads();
#pragma unroll
    for (int kd = 0; kd < 2; ++kd) {
      int cb = (kd * 32 + ((lane >> 4) & 3) * 8) * 2;
      bf16x8 af[4], wf[4];
#pragma unroll
      for (int mi = 0; mi < 4; ++mi) {
        int row = wrow + mi * 16 + (lane & 15);
        af[mi] = *(const bf16x8*)(lds + row * 128 + (cb ^ ((row & 7) << 4)));
      }
#pragma unroll
      for (int ni = 0; ni < 4; ++ni) {
        int row = wcol + ni * 16 + (lane & 15);
        wf[ni] = *(const bf16x8*)(lds + 16384 + row * 128 + (cb ^ ((row & 7) << 4)));
      }
#pragma unroll
      for (int mi = 0; mi < 4; ++mi)
#pragma unroll
        for (int ni = 0; ni < 4; ++ni)
          acc[mi][ni] =
              __builtin_amdgcn_mfma_f32_16x16x32_bf16(af[mi], wf[ni], acc[mi][ni], 0, 0, 0);
    }
  }

  if (mode == 0) {
#pragma unroll
    for (int mi = 0; mi < 4; ++mi)
#pragma unroll
      for (int ni = 0; ni < 4; ++ni) {
        int n = nb * 128 + wcol + ni * 16 + (lane & 15);
        int h = n >> 6, d = n & 63;
        float bn = bias[n];
#pragma unroll
        for (int j = 0; j < 4; ++j) {
          int m = mb * 128 + wrow + mi * 16 + ((lane >> 4) & 3) * 4 + j;
          int b = m >> 10, t = m & 1023;
          out[(((size_t)(b * H_ + h)) * 1024 + t) * 64 + d] = f2bf(acc[mi][ni][j] + bn);
        }
      }
  } else {
#pragma unroll
    for (int mi = 0; mi < 4; ++mi)
#pragma unroll
      for (int ni = 0; ni < 4; ++ni) {
        int n = nb * 128 + wcol + ni * 16 + (lane & 15);
        int h = n >> 6, d = n & 63;
        float bn = bias[n];
        u16x4 pk;
#pragma unroll
        for (int j = 0; j < 4; ++j) pk[j] = f2bf(acc[mi][ni][j] + bn);
        int m0 = mb * 128 + wrow + mi * 16 + ((lane >> 4) & 3) * 4;
        int b = m0 >> 10, t0 = m0 & 1023;
        *(u16x4*)(out + (((size_t)(b * H_ + h)) * 64 + d) * 1024 + t0) = pk;
      }
  }
}

// ------------------------------------------------- fused flash attn + beta@V
// grid (TQ/128, H, B), 256 threads (4 waves x 32 q-rows)
__global__ __launch_bounds__(256)
void attn_fused(const unsigned short* __restrict__ qh,
                const unsigned short* __restrict__ kh,
                const unsigned short* __restrict__ vT,
                const unsigned short* __restrict__ bt,
                const int* __restrict__ src_mask,
                const int* __restrict__ tgt_mask,
                float* __restrict__ out) {
  __shared__ char lds[49152];
  // K [64][128B] @0 ; VT [64][128B] @8192 ; beta [128][128B] @16384 ; P [128][128B] @32768
  const int tid = threadIdx.x, lane = tid & 63, wid = tid >> 6;
  const int qb = blockIdx.x, h = blockIdx.y, b = blockIdx.z;

  const unsigned short* qbh = qh + ((size_t)(b * H_ + h)) * TQ_ * 64;
  const char* kbh = (const char*)(kh + ((size_t)(b * H_ + h)) * TK_ * 64);
  const char* vbh = (const char*)(vT + ((size_t)(b * H_ + h)) * 64 * TK_);
  const char* bbh = (const char*)(bt + ((size_t)h) * TQ_ * TK_);

  // hoist Q fragments to registers (A-layout reads straight from global)
  bf16x8 qf[2][2];
#pragma unroll
  for (int mi = 0; mi < 2; ++mi)
#pragma unroll
    for (int kd = 0; kd < 2; ++kd) {
      int row = qb * 128 + wid * 32 + mi * 16 + (lane & 15);
      int k0 = kd * 32 + ((lane >> 4) & 3) * 8;
      qf[mi][kd] = *(const bf16x8*)(qbh + (size_t)row * 64 + k0);
    }

  bool tok[2][4];
#pragma unroll
  for (int mi = 0; mi < 2; ++mi)
#pragma unroll
    for (int j = 0; j < 4; ++j) {
      int row = qb * 128 + wid * 32 + mi * 16 + ((lane >> 4) & 3) * 4 + j;
      tok[mi][j] = tgt_mask[b * TQ_ + row] != 0;
    }

  f32x4 op[2][4], ob[2][4];
#pragma unroll
  for (int mi = 0; mi < 2; ++mi)
#pragma unroll
    for (int di = 0; di < 4; ++di)
#pragma unroll
      for (int t = 0; t < 4; ++t) { op[mi][di][t] = 0.f; ob[mi][di][t] = 0.f; }
  float m_r[2][4], l_r[2][4];
#pragma unroll
  for (int mi = 0; mi < 2; ++mi)
#pragma unroll
    for (int j = 0; j < 4; ++j) { m_r[mi][j] = -3.0e38f; l_r[mi][j] = 0.f; }

  for (int kt = 0; kt < 16; ++kt) {
    __syncthreads();
    // stage K (8KB, contiguous), VT (8KB), beta (16KB) -- 32 calls, 8 per wave
#pragma unroll
    for (int c = 0; c < 8; ++c) {
      int id = wid * 8 + c;
      if (id < 8) {
        int o = id * 1024 + lane * 16;
        int l = swz(o);
        gload16(lds + id * 1024, kbh + (size_t)kt * 8192 + l);
      } else if (id < 16) {
        int o = (id - 8) * 1024 + lane * 16;
        int l = swz(o);
        gload16(lds + 8192 + (id - 8) * 1024,
                vbh + (size_t)(l >> 7) * 2048 + kt * 128 + (l & 127));
      } else {
        int o = (id - 16) * 1024 + lane * 16;
        int l = swz(o);
        gload16(lds + 16384 + (id - 16) * 1024,
                bbh + (size_t)(qb * 128 + (l >> 7)) * 2048 + kt * 128 + (l & 127));
      }
    }
    __syncthreads();

    // S = Q K^T  (C-layout fragments)
    f32x4 s[2][4];
#pragma unroll
    for (int mi = 0; mi < 2; ++mi)
#pragma unroll
      for (int ni = 0; ni < 4; ++ni)
#pragma unroll
        for (int t = 0; t < 4; ++t) s[mi][ni][t] = 0.f;
#pragma unroll
    for (int kd = 0; kd < 2; ++kd) {
      int cb = (kd * 32 + ((lane >> 4) & 3) * 8) * 2;
      bf16x8 kf[4];
#pragma unroll
      for (int ni = 0; ni < 4; ++ni) {
        int row = ni * 16 + (lane & 15);
        kf[ni] = *(const bf16x8*)(lds + row * 128 + (cb ^ ((row & 7) << 4)));
      }
#pragma unroll
      for (int mi = 0; mi < 2; ++mi)
#pragma unroll
        for (int ni = 0; ni < 4; ++ni)
          s[mi][ni] =
              __builtin_amdgcn_mfma_f32_16x16x32_bf16(qf[mi][kd], kf[ni], s[mi][ni], 0, 0, 0);
    }

    bool sok[4];
#pragma unroll
    for (int ni = 0; ni < 4; ++ni)
      sok[ni] = src_mask[b * TK_ + kt * 64 + ni * 16 + (lane & 15)] != 0;

    // online softmax (wave-parallel, 16-lane butterfly per row group)
#pragma unroll
    for (int mi = 0; mi < 2; ++mi) {
#pragma unroll
      for (int j = 0; j < 4; ++j) {
        float rmax = -3.0e38f;
#pragma unroll
        for (int ni = 0; ni < 4; ++ni) {
          float v = (sok[ni] && tok[mi][j]) ? s[mi][ni][j] * SCALE_ : NEG_;
          s[mi][ni][j] = v;
          rmax = fmaxf(rmax, v);
        }
#pragma unroll
        for (int x = 1; x < 16; x <<= 1) rmax = fmaxf(rmax, __shfl_xor(rmax, x));
        float mo = m_r[mi][j];
        float mn = fmaxf(mo, rmax);
        m_r[mi][j] = mn;
        float corr = __expf(mo - mn);
        float lsum = 0.f;
#pragma unroll
        for (int ni = 0; ni < 4; ++ni) {
          float p = __expf(s[mi][ni][j] - mn);
          s[mi][ni][j] = p;
          lsum += p;
        }
#pragma unroll
        for (int x = 1; x < 16; x <<= 1) lsum += __shfl_xor(lsum, x);
        l_r[mi][j] = l_r[mi][j] * corr + lsum;
#pragma unroll
        for (int di = 0; di < 4; ++di) op[mi][di][j] *= corr;
        // write P (bf16) to swizzled LDS, per-wave region
        int prow = wid * 32 + mi * 16 + ((lane >> 4) & 3) * 4 + j;
#pragma unroll
        for (int ni = 0; ni < 4; ++ni) {
          int colb = (ni * 16 + (lane & 15)) * 2;
          *(unsigned short*)(lds + 32768 + prow * 128 + (colb ^ ((prow & 7) << 4))) =
              f2bf(s[mi][ni][j]);
        }
      }
    }

    // O_p += P @ V ; O_b += beta @ V   (shared VT fragments)
#pragma unroll
    for (int ks = 0; ks < 2; ++ks) {
      int cb = (ks * 32 + ((lane >> 4) & 3) * 8) * 2;
      bf16x8 vf[4];
#pragma unroll
      for (int di = 0; di < 4; ++di) {
        int row = di * 16 + (lane & 15);
        vf[di] = *(const bf16x8*)(lds + 8192 + row * 128 + (cb ^ ((row & 7) << 4)));
      }
#pragma unroll
      for (int mi = 0; mi < 2; ++mi) {
        int prow = wid * 32 + mi * 16 + (lane & 15);
        bf16x8 pf = *(const bf16x8*)(lds + 32768 + prow * 128 + (cb ^ ((prow & 7) << 4)));
        bf16x8 bf_ = *(const bf16x8*)(lds + 16384 + prow * 128 + (cb ^ ((prow & 7) << 4)));
#pragma unroll
        for (int di = 0; di < 4; ++di) {
          op[mi][di] = __builtin_amdgcn_mfma_f32_16x16x32_bf16(pf, vf[di], op[mi][di], 0, 0, 0);
          ob[mi][di] = __builtin_amdgcn_mfma_f32_16x16x32_bf16(bf_, vf[di], ob[mi][di], 0, 0, 0);
        }
      }
    }
  }

  // epilogue: out[b, q, h*64+d] = O_p/l + O_b  (fp32)
#pragma unroll
  for (int mi = 0; mi < 2; ++mi)
#pragma unroll
    for (int j = 0; j < 4; ++j) {
      float inv = 1.0f / l_r[mi][j];
      int row = qb * 128 + wid * 32 + mi * 16 + ((lane >> 4) & 3) * 4 + j;
#pragma unroll
      for (int di = 0; di < 4; ++di) {
        int d = di * 16 + (lane & 15);
        out[((size_t)b * TQ_ + row) * DIM_ + h * 64 + d] = op[mi][di][j] * inv + ob[mi][di][j];
      }
    }
}

// -------------------------------------------------------------------- launch
extern "C" void kernel_launch(void* const* d_in, const int* in_sizes, int n_in,
                              void* d_out, int out_size, void* d_ws, size_t ws_size,
                              hipStream_t stream) {
  const float* q    = (const float*)d_in[0];
  const float* k    = (const float*)d_in[1];
  const float* v    = (const float*)d_in[2];
  const float* beta = (const float*)d_in[3];
  const int* src_mask = (const int*)d_in[4];
  const int* tgt_mask = (const int*)d_in[5];
  const float* Wq = (const float*)d_in[6];
  const float* bq = (const float*)d_in[7];
  const float* Wk = (const float*)d_in[8];
  const float* bk = (const float*)d_in[9];
  const float* Wv = (const float*)d_in[10];
  const float* bv = (const float*)d_in[11];
  float* out = (float*)d_out;

  unsigned short* ws = (unsigned short*)d_ws;
  const size_t SZ = (size_t)B_ * TQ_ * DIM_;  // 8M elements
  unsigned short* qb16 = ws;
  unsigned short* kb16 = qb16 + SZ;
  unsigned short* vb16 = kb16 + SZ;
  unsigned short* Wqb  = vb16 + SZ;
  unsigned short* Wkb  = Wqb + (size_t)DIM_ * DIM_;
  unsigned short* Wvb  = Wkb + (size_t)DIM_ * DIM_;
  unsigned short* qhB  = Wvb + (size_t)DIM_ * DIM_;
  unsigned short* khB  = qhB + SZ;
  unsigned short* vTB  = khB + SZ;
  unsigned short* btB  = vTB + SZ;  // [H,TQ,TK] bf16

  cvt_f32_bf16<<<2048, 256, 0, stream>>>(q, qb16, (int)(SZ / 4));
  cvt_f32_bf16<<<2048, 256, 0, stream>>>(k, kb16, (int)(SZ / 4));
  cvt_f32_bf16<<<2048, 256, 0, stream>>>(v, vb16, (int)(SZ / 4));
  cvt_f32_bf16<<<512, 256, 0, stream>>>(Wq, Wqb, (DIM_ * DIM_) / 4);
  cvt_f32_bf16<<<512, 256, 0, stream>>>(Wk, Wkb, (DIM_ * DIM_) / 4);
  cvt_f32_bf16<<<512, 256, 0, stream>>>(Wv, Wvb, (DIM_ * DIM_) / 4);
  cvt_f32_bf16<<<2048, 256, 0, stream>>>(beta, btB, (H_ * TQ_ * TK_) / 4);

  dim3 ggrid(64, 8);
  proj_gemm<<<ggrid, 256, 0, stream>>>(qb16, Wqb, bq, qhB, 0);
  proj_gemm<<<ggrid, 256, 0, stream>>>(kb16, Wkb, bk, khB, 0);
  proj_gemm<<<ggrid, 256, 0, stream>>>(vb16, Wvb, bv, vTB, 1);

  dim3 agrid(TQ_ / 128, H_, B_);
  attn_fused<<<agrid, 256, 0, stream>>>(qhB, khB, vTB, btB, src_mask, tgt_mask, out);
}

// Round 7
// 396.693 us; speedup vs baseline: 1.3889x; 1.3889x over previous
//
#include <hip/hip_runtime.h>
#include <hip/hip_bf16.h>

// Problem constants
#define B_   8
#define TQ_  1024
#define TK_  1024
#define DIM_ 1024
#define H_   16
#define D_   64
#define SCALE_ 0.03125f   // DIM^-0.5
#define NEG_  -1.0e9f
#define LOG2E_ 1.4426950408889634f

typedef __attribute__((ext_vector_type(8))) short bf16x8;
typedef __attribute__((ext_vector_type(4))) float f32x4;
typedef __attribute__((ext_vector_type(4))) unsigned short u16x4;

typedef void __attribute__((address_space(3))) lds_void;
typedef const void __attribute__((address_space(1))) g_void;

__device__ __forceinline__ unsigned short f2bf(float f) {
  unsigned int u = __float_as_uint(f);
  u += 0x7fffu + ((u >> 16) & 1u);   // RNE to bf16
  return (unsigned short)(u >> 16);
}

// XOR swizzle for tiles with 128-byte rows (involution).
__device__ __forceinline__ int swz(int o) { return o ^ (((o >> 7) & 7) << 4); }

__device__ __forceinline__ void gload16(char* l, const char* g) {
  __builtin_amdgcn_global_load_lds((g_void*)g, (lds_void*)l, 16, 0, 0);
}

// ---------------------------------------------------------------- conversions
// 3-way f32 -> bf16 converter; blockIdx.y selects the tensor.
__global__ void cvt3(const float* __restrict__ s0, const float* __restrict__ s1,
                     const float* __restrict__ s2,
                     unsigned short* __restrict__ d0, unsigned short* __restrict__ d1,
                     unsigned short* __restrict__ d2, int n4) {
  const float* s = blockIdx.y == 0 ? s0 : blockIdx.y == 1 ? s1 : s2;
  unsigned short* d = blockIdx.y == 0 ? d0 : blockIdx.y == 1 ? d1 : d2;
  int idx = blockIdx.x * blockDim.x + threadIdx.x;
  int stride = gridDim.x * blockDim.x;
  for (int i = idx; i < n4; i += stride) {
    f32x4 v = ((const f32x4*)s)[i];
    u16x4 o;
#pragma unroll
    for (int j = 0; j < 4; ++j) o[j] = f2bf(v[j]);
    ((u16x4*)d)[i] = o;
  }
}

// ------------------------------------------------------------ projection GEMM
// All three projections in one dispatch; blockIdx.z selects {Q,K,V}.
// z==0 (Q): out [B,H,T,64], scaled by SCALE*LOG2E (softmax works in log2 domain)
// z==1 (K): out [B,H,T,64]
// z==2 (V): out [B,H,64,T] (transposed, MFMA-B-operand-ready)
// grid (nb, mb, z): consecutive ids share nb -> same XCD reuses the W-panel.
__global__ __launch_bounds__(256)
void proj_gemm(const unsigned short* __restrict__ qA, const unsigned short* __restrict__ kA,
               const unsigned short* __restrict__ vA,
               const unsigned short* __restrict__ Wqp, const unsigned short* __restrict__ Wkp,
               const unsigned short* __restrict__ Wvp,
               const float* __restrict__ bqp, const float* __restrict__ bkp,
               const float* __restrict__ bvp,
               unsigned short* __restrict__ qO, unsigned short* __restrict__ kO,
               unsigned short* __restrict__ vO) {
  const int z = blockIdx.z;
  const unsigned short* A = z == 0 ? qA : z == 1 ? kA : vA;
  const unsigned short* W = z == 0 ? Wqp : z == 1 ? Wkp : Wvp;
  const float* bias = z == 0 ? bqp : z == 1 ? bkp : bvp;
  unsigned short* out = z == 0 ? qO : z == 1 ? kO : vO;
  const float scale = (z == 0) ? SCALE_ * LOG2E_ : 1.0f;
  const int mode = (z == 2) ? 1 : 0;

  __shared__ char lds[32768];  // A tile [128][64]bf16 @0, W tile @16384
  const int tid = threadIdx.x;
  const int lane = tid & 63, wid = tid >> 6;
  const int nb = blockIdx.x, mb = blockIdx.y;
  const int wrow = (wid >> 1) * 64, wcol = (wid & 1) * 64;

  f32x4 acc[4][4];
#pragma unroll
  for (int mi = 0; mi < 4; ++mi)
#pragma unroll
    for (int ni = 0; ni < 4; ++ni)
#pragma unroll
      for (int t = 0; t < 4; ++t) acc[mi][ni][t] = 0.f;

  const char* Ab = (const char*)A + (size_t)mb * 128 * 2048;
  const char* Wb = (const char*)W + (size_t)nb * 128 * 2048;

  for (int kt = 0; kt < 16; ++kt) {
    __syncthreads();
#pragma unroll
    for (int c = 0; c < 4; ++c) {
      int o = (wid * 4 + c) * 1024 + lane * 16;
      int l = swz(o);
      gload16(lds + (wid * 4 + c) * 1024,
              Ab + (size_t)(l >> 7) * 2048 + kt * 128 + (l & 127));
      gload16(lds + 16384 + (wid * 4 + c) * 1024,
              Wb + (size_t)(l >> 7) * 2048 + kt * 128 + (l & 127));
    }
    __syncthreads();
#pragma unroll
    for (int kd = 0; kd < 2; ++kd) {
      int cb = (kd * 32 + ((lane >> 4) & 3) * 8) * 2;
      bf16x8 af[4], wf[4];
#pragma unroll
      for (int mi = 0; mi < 4; ++mi) {
        int row = wrow + mi * 16 + (lane & 15);
        af[mi] = *(const bf16x8*)(lds + row * 128 + (cb ^ ((row & 7) << 4)));
      }
#pragma unroll
      for (int ni = 0; ni < 4; ++ni) {
        int row = wcol + ni * 16 + (lane & 15);
        wf[ni] = *(const bf16x8*)(lds + 16384 + row * 128 + (cb ^ ((row & 7) << 4)));
      }
      __builtin_amdgcn_s_setprio(1);
#pragma unroll
      for (int mi = 0; mi < 4; ++mi)
#pragma unroll
        for (int ni = 0; ni < 4; ++ni)
          acc[mi][ni] =
              __builtin_amdgcn_mfma_f32_16x16x32_bf16(af[mi], wf[ni], acc[mi][ni], 0, 0, 0);
      __builtin_amdgcn_s_setprio(0);
    }
  }

  if (mode == 0) {
#pragma unroll
    for (int mi = 0; mi < 4; ++mi)
#pragma unroll
      for (int ni = 0; ni < 4; ++ni) {
        int n = nb * 128 + wcol + ni * 16 + (lane & 15);
        int h = n >> 6, d = n & 63;
        float bn = bias[n];
#pragma unroll
        for (int j = 0; j < 4; ++j) {
          int m = mb * 128 + wrow + mi * 16 + ((lane >> 4) & 3) * 4 + j;
          int b = m >> 10, t = m & 1023;
          out[(((size_t)(b * H_ + h)) * 1024 + t) * 64 + d] =
              f2bf((acc[mi][ni][j] + bn) * scale);
        }
      }
  } else {
#pragma unroll
    for (int mi = 0; mi < 4; ++mi)
#pragma unroll
      for (int ni = 0; ni < 4; ++ni) {
        int n = nb * 128 + wcol + ni * 16 + (lane & 15);
        int h = n >> 6, d = n & 63;
        float bn = bias[n];
        u16x4 pk;
#pragma unroll
        for (int j = 0; j < 4; ++j) pk[j] = f2bf(acc[mi][ni][j] + bn);
        int m0 = mb * 128 + wrow + mi * 16 + ((lane >> 4) & 3) * 4;
        int b = m0 >> 10, t0 = m0 & 1023;
        *(u16x4*)(out + (((size_t)(b * H_ + h)) * 64 + d) * 1024 + t0) = pk;
      }
  }
}

// ------------------------------------------------- fused flash attn + beta@V
// grid (H, B, TQ/128), 256 threads (4 waves x 32 q-rows).
// Swapped QK^T (S^T = mfma(K,Q)): lane holds 16 k per q-row -> 2 shuffles/reduce.
// Softmax state (m,l,corr) lives on q=lane&15; PV accumulator rows are q=g*4+t,
// so corr (and 1/l in the epilogue) are redistributed via __shfl(.., g*4+t).
// K/V double-buffered in LDS via T14 reg-staging; one __syncthreads per
// iteration; all waitcnts compiler-managed. beta read as A-fragments from global.
__global__ __launch_bounds__(256)
void attn_fused(const unsigned short* __restrict__ qh,
                const unsigned short* __restrict__ kh,
                const unsigned short* __restrict__ vT,
                const unsigned short* __restrict__ bt,
                const int* __restrict__ src_mask,
                const int* __restrict__ tgt_mask,
                float* __restrict__ out) {
  __shared__ char lds[49152];
  // K dbuf @0,@8192 ; V dbuf @16384,@24576 ; P per-wave 4KB @32768
  const int tid = threadIdx.x, lane = tid & 63, wid = tid >> 6;
  const int h = blockIdx.x, b = blockIdx.y, qb = blockIdx.z;
  const int g = lane >> 4;           // 0..3 (16-lane group)
  const int lq = lane & 15;

  const unsigned short* qbh = qh + ((size_t)(b * H_ + h)) * TQ_ * 64;
  const char* kbh = (const char*)(kh + ((size_t)(b * H_ + h)) * TK_ * 64);
  const char* vbh = (const char*)(vT + ((size_t)(b * H_ + h)) * 64 * TK_);
  const char* bbh = (const char*)(bt + (size_t)h * TQ_ * TK_);

  // Q fragments (pre-scaled by SCALE*LOG2E in projection); B-operand layout
  // equals A-operand layout, so these serve directly in mfma(K,Q).
  bf16x8 qf[2][2];
#pragma unroll
  for (int mi = 0; mi < 2; ++mi)
#pragma unroll
    for (int kd = 0; kd < 2; ++kd) {
      int row = qb * 128 + wid * 32 + mi * 16 + lq;
      qf[mi][kd] = *(const bf16x8*)(qbh + (size_t)row * 64 + kd * 32 + g * 8);
    }

  bool tok[2];
#pragma unroll
  for (int mi = 0; mi < 2; ++mi)
    tok[mi] = tgt_mask[b * TQ_ + qb * 128 + wid * 32 + mi * 16 + lq] != 0;

  f32x4 op[2][4], ob[2][4];
#pragma unroll
  for (int mi = 0; mi < 2; ++mi)
#pragma unroll
    for (int di = 0; di < 4; ++di)
#pragma unroll
      for (int t = 0; t < 4; ++t) { op[mi][di][t] = 0.f; ob[mi][di][t] = 0.f; }
  float m_r[2] = {-3.0e38f, -3.0e38f};
  float l_r[2] = {0.f, 0.f};

  // T14 reg-staging buffers (static indices only -> stay in VGPRs)
  f32x4 kreg[2], vreg[2];

#define LOADREG(KT)                                                            \
  {                                                                            \
    _Pragma("unroll") for (int c = 0; c < 2; ++c) {                            \
      int o = (wid * 2 + c) * 1024 + lane * 16;                                \
      kreg[c] = *(const f32x4*)(kbh + (size_t)(KT)*8192 + o);                  \
      vreg[c] = *(const f32x4*)(vbh + (size_t)(o >> 7) * 2048 + (KT)*128 +     \
                                (o & 127));                                    \
    }                                                                          \
  }

#define WRITEREG(HB)                                                           \
  {                                                                            \
    _Pragma("unroll") for (int c = 0; c < 2; ++c) {                            \
      int o = (wid * 2 + c) * 1024 + lane * 16;                                \
      int l = swz(o);                                                          \
      *(f32x4*)(lds + (HB)*8192 + l) = kreg[c];                                \
      *(f32x4*)(lds + 16384 + (HB)*8192 + l) = vreg[c];                        \
    }                                                                          \
  }

  LOADREG(0);
  WRITEREG(0);

  for (int kt = 0; kt < 16; ++kt) {
    const int hb = kt & 1;
    if (kt < 15) LOADREG(kt + 1);  // issue next tile early; consumed by WRITEREG
    __syncthreads();               // makes buf[hb] writes visible; separates prev reads

    // beta A-fragments straight from global (issued early, used in PV)
    bf16x8 bfr[2][2];
#pragma unroll
    for (int mi = 0; mi < 2; ++mi)
#pragma unroll
      for (int ks = 0; ks < 2; ++ks) {
        int row = qb * 128 + wid * 32 + mi * 16 + lq;
        bfr[mi][ks] =
            *(const bf16x8*)(bbh + (size_t)row * 2048 + kt * 128 + ks * 64 + g * 16);
      }

    // src-mask bits for this tile via ballot: bit l = valid(k = kt*64+l).
    // Lane needs k = ni*16 + g*4 + j -> bit (ni*16+j) of (smask >> g*4).
    unsigned long long smask = __ballot(src_mask[b * TK_ + kt * 64 + lane] != 0);
    unsigned long long smg = smask >> (g * 4);

    // S^T = K Q^T : C[row=k][col=q]; lane holds q=lq(+16mi), k=(g*4+j)+16ni
    const char* Kb = lds + hb * 8192;
    const char* Vb = lds + 16384 + hb * 8192;
    char* Pw = lds + 32768 + wid * 4096;

    f32x4 s[4][2];
#pragma unroll
    for (int ni = 0; ni < 4; ++ni)
#pragma unroll
      for (int mi = 0; mi < 2; ++mi)
#pragma unroll
        for (int t = 0; t < 4; ++t) s[ni][mi][t] = 0.f;
#pragma unroll
    for (int kd = 0; kd < 2; ++kd) {
      int cb = (kd * 32 + g * 8) * 2;
      bf16x8 kf[4];
#pragma unroll
      for (int ni = 0; ni < 4; ++ni) {
        int row = ni * 16 + lq;
        kf[ni] = *(const bf16x8*)(Kb + row * 128 + (cb ^ ((row & 7) << 4)));
      }
      __builtin_amdgcn_s_setprio(1);
#pragma unroll
      for (int ni = 0; ni < 4; ++ni)
#pragma unroll
        for (int mi = 0; mi < 2; ++mi)
          s[ni][mi] =
              __builtin_amdgcn_mfma_f32_16x16x32_bf16(kf[ni], qf[mi][kd], s[ni][mi], 0, 0, 0);
      __builtin_amdgcn_s_setprio(0);
    }

    // online softmax in log2 domain (scores already carry log2e)
#pragma unroll
    for (int mi = 0; mi < 2; ++mi) {
      unsigned long long smv = tok[mi] ? smg : 0ull;
      float v[4][4];
      float rmax = -3.0e38f;
#pragma unroll
      for (int ni = 0; ni < 4; ++ni)
#pragma unroll
        for (int j = 0; j < 4; ++j) {
          bool ok = (smv >> (ni * 16 + j)) & 1ull;
          float x = ok ? s[ni][mi][j] : NEG_;
          v[ni][j] = x;
          rmax = fmaxf(rmax, x);
        }
      rmax = fmaxf(rmax, __shfl_xor(rmax, 16));
      rmax = fmaxf(rmax, __shfl_xor(rmax, 32));
      float mo = m_r[mi];
      float mn = fmaxf(mo, rmax);
      m_r[mi] = mn;
      float corr = exp2f(mo - mn);      // for q = mi*16 + lq
      float lsum = 0.f;
      u16x4 pk[4];
#pragma unroll
      for (int ni = 0; ni < 4; ++ni)
#pragma unroll
        for (int j = 0; j < 4; ++j) {
          float p = exp2f(v[ni][j] - mn);
          lsum += p;
          pk[ni][j] = f2bf(p);
        }
      lsum += __shfl_xor(lsum, 16);
      lsum += __shfl_xor(lsum, 32);
      l_r[mi] = l_r[mi] * corr + lsum;
      // op rows are q = mi*16 + g*4 + t -> fetch that row's corr from lane g*4+t
      float corR[4];
#pragma unroll
      for (int t = 0; t < 4; ++t) corR[t] = __shfl(corr, g * 4 + t);
#pragma unroll
      for (int di = 0; di < 4; ++di)
#pragma unroll
        for (int t = 0; t < 4; ++t) op[mi][di][t] *= corR[t];
      // P^T->P store: row q'=mi*16+lq, 4 consecutive k per (ni): one b64 each
      int qr = mi * 16 + lq;
#pragma unroll
      for (int ni = 0; ni < 4; ++ni)
        *(u16x4*)(Pw + qr * 128 + ((ni * 32 + g * 8) ^ ((qr & 7) << 4))) = pk[ni];
    }

    // O += P@V ; Ob += beta@V
#pragma unroll
    for (int ks = 0; ks < 2; ++ks) {
      int cb = (ks * 32 + g * 8) * 2;
      bf16x8 vf[4];
#pragma unroll
      for (int di = 0; di < 4; ++di) {
        int row = di * 16 + lq;
        vf[di] = *(const bf16x8*)(Vb + row * 128 + (cb ^ ((row & 7) << 4)));
      }
      bf16x8 pf[2];
#pragma unroll
      for (int mi = 0; mi < 2; ++mi) {
        int qr = mi * 16 + lq;
        pf[mi] = *(const bf16x8*)(Pw + qr * 128 + (cb ^ ((qr & 7) << 4)));
      }
      __builtin_amdgcn_s_setprio(1);
#pragma unroll
      for (int mi = 0; mi < 2; ++mi)
#pragma unroll
        for (int di = 0; di < 4; ++di) {
          op[mi][di] = __builtin_amdgcn_mfma_f32_16x16x32_bf16(pf[mi], vf[di], op[mi][di], 0, 0, 0);
          ob[mi][di] =
              __builtin_amdgcn_mfma_f32_16x16x32_bf16(bfr[mi][ks], vf[di], ob[mi][di], 0, 0, 0);
        }
      __builtin_amdgcn_s_setprio(0);
    }

    if (kt < 15) WRITEREG(hb ^ 1);  // safe: all waves passed this iter's barrier
  }

  // epilogue: O rows are q=(g*4+j); 1/l lives on lanes indexed by lq -> shfl
#pragma unroll
  for (int mi = 0; mi < 2; ++mi) {
    float invl = 1.0f / l_r[mi];
#pragma unroll
    for (int j = 0; j < 4; ++j) {
      float iv = __shfl(invl, g * 4 + j);
      int row = qb * 128 + wid * 32 + mi * 16 + g * 4 + j;
#pragma unroll
      for (int di = 0; di < 4; ++di) {
        int d = di * 16 + lq;
        out[((size_t)b * TQ_ + row) * DIM_ + h * 64 + d] = op[mi][di][j] * iv + ob[mi][di][j];
      }
    }
  }
#undef LOADREG
#undef WRITEREG
}

// -------------------------------------------------------------------- launch
extern "C" void kernel_launch(void* const* d_in, const int* in_sizes, int n_in,
                              void* d_out, int out_size, void* d_ws, size_t ws_size,
                              hipStream_t stream) {
  const float* q    = (const float*)d_in[0];
  const float* k    = (const float*)d_in[1];
  const float* v    = (const float*)d_in[2];
  const float* beta = (const float*)d_in[3];
  const int* src_mask = (const int*)d_in[4];
  const int* tgt_mask = (const int*)d_in[5];
  const float* Wq = (const float*)d_in[6];
  const float* bq = (const float*)d_in[7];
  const float* Wk = (const float*)d_in[8];
  const float* bk = (const float*)d_in[9];
  const float* Wv = (const float*)d_in[10];
  const float* bv = (const float*)d_in[11];
  float* out = (float*)d_out;

  unsigned short* ws = (unsigned short*)d_ws;
  const size_t SZ = (size_t)B_ * TQ_ * DIM_;  // 8M elements
  unsigned short* qb16 = ws;
  unsigned short* kb16 = qb16 + SZ;
  unsigned short* vb16 = kb16 + SZ;
  unsigned short* Wqb  = vb16 + SZ;
  unsigned short* Wkb  = Wqb + (size_t)DIM_ * DIM_;
  unsigned short* Wvb  = Wkb + (size_t)DIM_ * DIM_;
  unsigned short* qhB  = Wvb + (size_t)DIM_ * DIM_;
  unsigned short* khB  = qhB + SZ;
  unsigned short* vTB  = khB + SZ;
  unsigned short* btB  = vTB + SZ;  // [H,TQ,TK] bf16

  dim3 c1(1024, 3);
  cvt3<<<c1, 256, 0, stream>>>(q, k, v, qb16, kb16, vb16, (int)(SZ / 4));
  dim3 c2(128, 3);
  cvt3<<<c2, 256, 0, stream>>>(Wq, Wk, Wv, Wqb, Wkb, Wvb, (DIM_ * DIM_) / 4);
  dim3 c3(2048, 1);
  cvt3<<<c3, 256, 0, stream>>>(beta, beta, beta, btB, btB, btB, (H_ * TQ_ * TK_) / 4);

  dim3 ggrid(8, 64, 3);  // (nb, mb, z): same-nb blocks share an XCD's L2 W-panel
  proj_gemm<<<ggrid, 256, 0, stream>>>(qb16, kb16, vb16, Wqb, Wkb, Wvb, bq, bk, bv,
                                       qhB, khB, vTB);

  dim3 agrid(H_, B_, TQ_ / 128);  // (h, b, qb): same-(h,b) blocks share an XCD
  attn_fused<<<agrid, 256, 0, stream>>>(qhB, khB, vTB, btB, src_mask, tgt_mask, out);
}